// Round 6
// baseline (1865.068 us; speedup 1.0000x reference)
//
#include <hip/hip_runtime.h>
#include <math.h>

// MoDGMMFeatureModel, numpy-fp32-bit-exact (frozen op orders, proven round 3):
//  - sgemm: acc=0, sequential-k __builtin_fmaf, bias added AFTER (own rounding)
//  - LN mean/var: numpy pairwise 8-accumulator pattern
//  - elementwise: contract(off), left-assoc as written
//  - mod: fmodf + conditional += 2pi
// Round 6: round-3 skeleton (1 thread = 1 point, LDS only for activation
// columns, no barriers) + GEMMs j-chunked with 2-deep double-buffered VECTOR
// weight loads (wa/wb float4 arrays, static indices). Weights via VMEM+vmcnt
// pipelining instead of SMEM batch drains (round 3) or the LDS pipe (round 5,
// which was slower than the FMAs it fed and halved occupancy).

constexpr int N_PTS = 1000000;
constexpr int GW = 64;
constexpr int FDIM = 32;
constexpr int DIN = 34;          // 2 + 32
constexpr int NH1 = 128;
constexpr int NH2 = 64;
constexpr int NOUT = 48;         // 6 * 8
constexpr int NC = 8;
constexpr int BLK = 128;

// numpy pairwise_sum for N in {64,128} (8-accumulator pattern)
template<int N>
__device__ __forceinline__ float np_pairwise(const float* x) {
#pragma clang fp contract(off)
    float r[8];
#pragma unroll
    for (int j = 0; j < 8; ++j) r[j] = x[j];
#pragma unroll
    for (int m = 1; m < N / 8; ++m)
#pragma unroll
        for (int j = 0; j < 8; ++j) r[j] = r[j] + x[8 * m + j];
    return ((r[0] + r[1]) + (r[2] + r[3])) + ((r[4] + r[5]) + (r[6] + r[7]));
}

template<int N>
__device__ __forceinline__ float np_pairwise_sq(const float* x, float mu) {
#pragma clang fp contract(off)
    float r[8];
#pragma unroll
    for (int j = 0; j < 8; ++j) { const float d = x[j] - mu; r[j] = d * d; }
#pragma unroll
    for (int m = 1; m < N / 8; ++m)
#pragma unroll
        for (int j = 0; j < 8; ++j) {
            const float d = x[8 * m + j] - mu;
            r[j] = r[j] + d * d;
        }
    return ((r[0] + r[1]) + (r[2] + r[3])) + ((r[4] + r[5]) + (r[6] + r[7]));
}

__global__ __launch_bounds__(BLK, 2) void modgmm_np32_pipe(
    const float* __restrict__ coords,
    const float* __restrict__ grid,
    const float* __restrict__ W1, const float* __restrict__ b1,
    const float* __restrict__ g1, const float* __restrict__ be1,
    const float* __restrict__ W2, const float* __restrict__ b2,
    const float* __restrict__ g2, const float* __restrict__ be2,
    const float* __restrict__ W3, const float* __restrict__ b3,
    float* __restrict__ gmm_out, float* __restrict__ coords_out)
{
#pragma clang fp contract(off)
    __shared__ float sbuf[64 * BLK];   // 32 KB activation staging [row][tid]
    const int tid = threadIdx.x;
    const int i = blockIdx.x * BLK + tid;
    if (i >= N_PTS) return;            // no barriers anywhere: safe

    const float2 c2 = reinterpret_cast<const float2*>(coords)[i];
    const float cx = c2.x, cy = c2.y;

    // ---- bilinear gather, numpy op order (identical to round 3) ----
    const float x = cx * 63.0f;
    const float y = cy * 63.0f;
    int x0 = (int)floorf(x); x0 = x0 < 0 ? 0 : (x0 > 62 ? 62 : x0);
    int y0 = (int)floorf(y); y0 = y0 < 0 ? 0 : (y0 > 62 ? 62 : y0);
    const float dx = x - (float)x0;
    const float dy = y - (float)y0;
    const float omdx = 1.0f - dx;
    const float omdy = 1.0f - dy;
    const float w00 = omdx * omdy;
    const float w01 = omdx * dy;
    const float w10 = dx * omdy;
    const float w11 = dx * dy;

    const float* __restrict__ gp = grid + (y0 * GW + x0) * FDIM;

    sbuf[0 * BLK + tid] = cx;
    sbuf[1 * BLK + tid] = cy;
#pragma unroll
    for (int k = 0; k < FDIM; ++k) {
        const float t0 = w00 * gp[k];
        const float t1 = w01 * gp[GW * FDIM + k];
        const float t2 = w10 * gp[FDIM + k];
        const float t3 = w11 * gp[GW * FDIM + FDIM + k];
        sbuf[(2 + k) * BLK + tid] = ((t0 + t1) + t2) + t3;
    }

    // ---- layer 1: 34 -> 128 in 4 j-chunks of 32, dbuf'd weight rows ----
    float h[NH1];
#pragma unroll
    for (int jc = 0; jc < 4; ++jc) {
        const float* wbase = W1 + jc * 32;
        float acc[32];
#pragma unroll
        for (int jj = 0; jj < 32; ++jj) acc[jj] = 0.0f;
        float4 wa[8], wb[8];
#pragma unroll
        for (int q = 0; q < 8; ++q)
            wa[q] = *reinterpret_cast<const float4*>(wbase + 4 * q);
        for (int k = 0; k < DIN; k += 2) {
            const float hv0 = sbuf[k * BLK + tid];
            const float hv1 = sbuf[(k + 1) * BLK + tid];
#pragma unroll
            for (int q = 0; q < 8; ++q)
                wb[q] = *reinterpret_cast<const float4*>(wbase + (k + 1) * NH1 + 4 * q);
#pragma unroll
            for (int q = 0; q < 8; ++q) {
                acc[4*q+0] = __builtin_fmaf(hv0, wa[q].x, acc[4*q+0]);
                acc[4*q+1] = __builtin_fmaf(hv0, wa[q].y, acc[4*q+1]);
                acc[4*q+2] = __builtin_fmaf(hv0, wa[q].z, acc[4*q+2]);
                acc[4*q+3] = __builtin_fmaf(hv0, wa[q].w, acc[4*q+3]);
            }
            if (k + 2 < DIN) {
#pragma unroll
                for (int q = 0; q < 8; ++q)
                    wa[q] = *reinterpret_cast<const float4*>(wbase + (k + 2) * NH1 + 4 * q);
            }
#pragma unroll
            for (int q = 0; q < 8; ++q) {
                acc[4*q+0] = __builtin_fmaf(hv1, wb[q].x, acc[4*q+0]);
                acc[4*q+1] = __builtin_fmaf(hv1, wb[q].y, acc[4*q+1]);
                acc[4*q+2] = __builtin_fmaf(hv1, wb[q].z, acc[4*q+2]);
                acc[4*q+3] = __builtin_fmaf(hv1, wb[q].w, acc[4*q+3]);
            }
        }
#pragma unroll
        for (int jj = 0; jj < 32; ++jj) h[jc * 32 + jj] = acc[jj];
    }
#pragma unroll
    for (int j = 0; j < NH1; ++j) h[j] = fmaxf(h[j] + b1[j], 0.0f);

    // ---- layernorm 1 (identical to round 3) ----
    {
        const float mu = np_pairwise<NH1>(h) / 128.0f;
        const float var = np_pairwise_sq<NH1>(h, mu) / 128.0f;
        const float rs = 1.0f / sqrtf(var + 1e-5f);
#pragma unroll
        for (int j = 0; j < NH1; ++j)
            h[j] = ((h[j] - mu) * rs) * g1[j] + be1[j];
    }

    // ---- layer 2: 128 -> 64; k in two staged 64-row phases, j in 2 chunks ----
    float h2[NH2];
#pragma unroll
    for (int j = 0; j < NH2; ++j) h2[j] = 0.0f;
#pragma unroll
    for (int p = 0; p < 2; ++p) {
#pragma unroll
        for (int j = 0; j < 64; ++j) sbuf[j * BLK + tid] = h[p * 64 + j];
#pragma unroll
        for (int jc = 0; jc < 2; ++jc) {
            const float* wbase = W2 + (size_t)(p * 64) * NH2 + jc * 32;
            float acc[32];
#pragma unroll
            for (int jj = 0; jj < 32; ++jj) acc[jj] = h2[jc * 32 + jj];
            float4 wa[8], wb[8];
#pragma unroll
            for (int q = 0; q < 8; ++q)
                wa[q] = *reinterpret_cast<const float4*>(wbase + 4 * q);
            for (int kk = 0; kk < 64; kk += 2) {
                const float hv0 = sbuf[kk * BLK + tid];
                const float hv1 = sbuf[(kk + 1) * BLK + tid];
#pragma unroll
                for (int q = 0; q < 8; ++q)
                    wb[q] = *reinterpret_cast<const float4*>(wbase + (kk + 1) * NH2 + 4 * q);
#pragma unroll
                for (int q = 0; q < 8; ++q) {
                    acc[4*q+0] = __builtin_fmaf(hv0, wa[q].x, acc[4*q+0]);
                    acc[4*q+1] = __builtin_fmaf(hv0, wa[q].y, acc[4*q+1]);
                    acc[4*q+2] = __builtin_fmaf(hv0, wa[q].z, acc[4*q+2]);
                    acc[4*q+3] = __builtin_fmaf(hv0, wa[q].w, acc[4*q+3]);
                }
                if (kk + 2 < 64) {
#pragma unroll
                    for (int q = 0; q < 8; ++q)
                        wa[q] = *reinterpret_cast<const float4*>(wbase + (kk + 2) * NH2 + 4 * q);
                }
#pragma unroll
                for (int q = 0; q < 8; ++q) {
                    acc[4*q+0] = __builtin_fmaf(hv1, wb[q].x, acc[4*q+0]);
                    acc[4*q+1] = __builtin_fmaf(hv1, wb[q].y, acc[4*q+1]);
                    acc[4*q+2] = __builtin_fmaf(hv1, wb[q].z, acc[4*q+2]);
                    acc[4*q+3] = __builtin_fmaf(hv1, wb[q].w, acc[4*q+3]);
                }
            }
#pragma unroll
            for (int jj = 0; jj < 32; ++jj) h2[jc * 32 + jj] = acc[jj];
        }
    }
#pragma unroll
    for (int j = 0; j < NH2; ++j) h2[j] = fmaxf(h2[j] + b2[j], 0.0f);

    // ---- layernorm 2 ----
    {
        const float mu = np_pairwise<NH2>(h2) / 64.0f;
        const float var = np_pairwise_sq<NH2>(h2, mu) / 64.0f;
        const float rs = 1.0f / sqrtf(var + 1e-5f);
#pragma unroll
        for (int j = 0; j < NH2; ++j)
            h2[j] = ((h2[j] - mu) * rs) * g2[j] + be2[j];
    }

    // ---- layer 3: 64 -> 48 in 2 j-chunks of 24 ----
#pragma unroll
    for (int j = 0; j < NH2; ++j) sbuf[j * BLK + tid] = h2[j];
    float o[NOUT];
#pragma unroll
    for (int jc = 0; jc < 2; ++jc) {
        const float* wbase = W3 + jc * 24;
        float acc[24];
#pragma unroll
        for (int jj = 0; jj < 24; ++jj) acc[jj] = 0.0f;
        float4 wa[6], wb[6];
#pragma unroll
        for (int q = 0; q < 6; ++q)
            wa[q] = *reinterpret_cast<const float4*>(wbase + 4 * q);
        for (int k = 0; k < NH2; k += 2) {
            const float hv0 = sbuf[k * BLK + tid];
            const float hv1 = sbuf[(k + 1) * BLK + tid];
#pragma unroll
            for (int q = 0; q < 6; ++q)
                wb[q] = *reinterpret_cast<const float4*>(wbase + (k + 1) * NOUT + 4 * q);
#pragma unroll
            for (int q = 0; q < 6; ++q) {
                acc[4*q+0] = __builtin_fmaf(hv0, wa[q].x, acc[4*q+0]);
                acc[4*q+1] = __builtin_fmaf(hv0, wa[q].y, acc[4*q+1]);
                acc[4*q+2] = __builtin_fmaf(hv0, wa[q].z, acc[4*q+2]);
                acc[4*q+3] = __builtin_fmaf(hv0, wa[q].w, acc[4*q+3]);
            }
            if (k + 2 < NH2) {
#pragma unroll
                for (int q = 0; q < 6; ++q)
                    wa[q] = *reinterpret_cast<const float4*>(wbase + (k + 2) * NOUT + 4 * q);
            }
#pragma unroll
            for (int q = 0; q < 6; ++q) {
                acc[4*q+0] = __builtin_fmaf(hv1, wb[q].x, acc[4*q+0]);
                acc[4*q+1] = __builtin_fmaf(hv1, wb[q].y, acc[4*q+1]);
                acc[4*q+2] = __builtin_fmaf(hv1, wb[q].z, acc[4*q+2]);
                acc[4*q+3] = __builtin_fmaf(hv1, wb[q].w, acc[4*q+3]);
            }
        }
#pragma unroll
        for (int jj = 0; jj < 24; ++jj) o[jc * 24 + jj] = acc[jj];
    }
#pragma unroll
    for (int j = 0; j < NOUT; ++j) o[j] = o[j] + b3[j];

    // ---- GMM postprocess (identical to round 3) ----
    const float TPf = 6.28318530717958647692f;
    float res[NOUT];
    float m = o[0];
#pragma unroll
    for (int c = 1; c < NC; ++c) m = fmaxf(m, o[6 * c]);
    float e[NC];
#pragma unroll
    for (int c = 0; c < NC; ++c) e[c] = expf(o[6 * c] - m);
    const float esum = ((e[0] + e[1]) + (e[2] + e[3])) + ((e[4] + e[5]) + (e[6] + e[7]));
#pragma unroll
    for (int c = 0; c < NC; ++c) {
        res[6 * c + 0] = e[c] / esum;
        res[6 * c + 1] = fmaxf(o[6 * c + 1], 0.0f);
        float a = fmodf(o[6 * c + 2], TPf);
        if (a < 0.0f) a += TPf;
        res[6 * c + 2] = a;
        res[6 * c + 3] = expf(fminf(fmaxf(o[6 * c + 3], -10.0f), 10.0f));
        res[6 * c + 4] = expf(fminf(fmaxf(o[6 * c + 4], -10.0f), 10.0f));
        res[6 * c + 5] = 0.99f * tanhf(o[6 * c + 5]);
    }

    // ---- stores (coalesced, 192 B contiguous per thread) ----
    float4* og = reinterpret_cast<float4*>(gmm_out + (size_t)i * NOUT);
#pragma unroll
    for (int q = 0; q < NOUT / 4; ++q)
        og[q] = make_float4(res[4 * q + 0], res[4 * q + 1], res[4 * q + 2], res[4 * q + 3]);
    reinterpret_cast<float2*>(coords_out)[i] = make_float2(cx, cy);
}

extern "C" void kernel_launch(void* const* d_in, const int* in_sizes, int n_in,
                              void* d_out, int out_size, void* d_ws, size_t ws_size,
                              hipStream_t stream) {
    const float* coords = (const float*)d_in[0];
    const float* grid   = (const float*)d_in[1];
    const float* W1  = (const float*)d_in[2];
    const float* b1  = (const float*)d_in[3];
    const float* g1  = (const float*)d_in[4];
    const float* be1 = (const float*)d_in[5];
    const float* W2  = (const float*)d_in[6];
    const float* b2  = (const float*)d_in[7];
    const float* g2  = (const float*)d_in[8];
    const float* be2 = (const float*)d_in[9];
    const float* W3  = (const float*)d_in[10];
    const float* b3  = (const float*)d_in[11];

    float* gmm_out    = (float*)d_out;                          // N*48 floats
    float* coords_out = (float*)d_out + (size_t)N_PTS * NOUT;   // N*2 floats

    const int nblocks = (N_PTS + BLK - 1) / BLK;
    modgmm_np32_pipe<<<nblocks, BLK, 0, stream>>>(
        coords, grid, W1, b1, g1, be1, W2, b2, g2, be2, W3, b3,
        gmm_out, coords_out);
}

// Round 7
// 1749.262 us; speedup vs baseline: 1.0662x; 1.0662x over previous
//
#include <hip/hip_runtime.h>
#include <math.h>

// MoDGMMFeatureModel, numpy-fp32-bit-exact (frozen op orders, proven round 3):
//  - sgemm: acc=0, sequential-k __builtin_fmaf, bias added AFTER (own rounding)
//  - LN mean/var: numpy pairwise 8-accumulator pattern
//  - elementwise: contract(off), left-assoc as written
//  - mod: fmodf + conditional += 2pi
// Round 7: two-kernel split with TRANSPOSED h1 workspace (h1t[128][N]) so no
// kernel ever holds a 128-deep register array:
//  K1: gather + L1, j-range split per wave (uniform via readfirstlane),
//      acc[64]+f[34] ~ 110 regs -> 4 waves/SIMD; transposed coalesced stores.
//  K23: 1 thread/pt, ZERO LDS; LN1 stats streamed from h1t (coalesced, numpy
//      r[8] order), GEMM2 with on-the-fly normalize, in-reg LN2, unrolled
//      GEMM3, postprocess. ~130 regs -> 3 waves/SIMD.
// Round-3 monolith kept as fallback when ws is too small.

constexpr int N_PTS = 1000000;
constexpr int GW = 64;
constexpr int FDIM = 32;
constexpr int DIN = 34;
constexpr int NH1 = 128;
constexpr int NH2 = 64;
constexpr int NOUT = 48;
constexpr int NC = 8;

// ---------- numpy pairwise helpers (register arrays, static indices) ----------
template<int N>
__device__ __forceinline__ float np_pairwise(const float* x) {
#pragma clang fp contract(off)
    float r[8];
#pragma unroll
    for (int j = 0; j < 8; ++j) r[j] = x[j];
#pragma unroll
    for (int m = 1; m < N / 8; ++m)
#pragma unroll
        for (int j = 0; j < 8; ++j) r[j] = r[j] + x[8 * m + j];
    return ((r[0] + r[1]) + (r[2] + r[3])) + ((r[4] + r[5]) + (r[6] + r[7]));
}

template<int N>
__device__ __forceinline__ float np_pairwise_sq(const float* x, float mu) {
#pragma clang fp contract(off)
    float r[8];
#pragma unroll
    for (int j = 0; j < 8; ++j) { const float d = x[j] - mu; r[j] = d * d; }
#pragma unroll
    for (int m = 1; m < N / 8; ++m)
#pragma unroll
        for (int j = 0; j < 8; ++j) {
            const float d = x[8 * m + j] - mu;
            r[j] = r[j] + d * d;
        }
    return ((r[0] + r[1]) + (r[2] + r[3])) + ((r[4] + r[5]) + (r[6] + r[7]));
}

// ---------- shared device snippets ----------
__device__ __forceinline__ void gmm_postprocess_store(
    const float* o, float cx, float cy, int gi,
    float* __restrict__ gmm_out, float* __restrict__ coords_out)
{
#pragma clang fp contract(off)
    const float TPf = 6.28318530717958647692f;
    float res[NOUT];
    float m = o[0];
#pragma unroll
    for (int c = 1; c < NC; ++c) m = fmaxf(m, o[6 * c]);
    float e[NC];
#pragma unroll
    for (int c = 0; c < NC; ++c) e[c] = expf(o[6 * c] - m);
    const float esum = ((e[0] + e[1]) + (e[2] + e[3])) + ((e[4] + e[5]) + (e[6] + e[7]));
#pragma unroll
    for (int c = 0; c < NC; ++c) {
        res[6 * c + 0] = e[c] / esum;
        res[6 * c + 1] = fmaxf(o[6 * c + 1], 0.0f);
        float a = fmodf(o[6 * c + 2], TPf);
        if (a < 0.0f) a += TPf;
        res[6 * c + 2] = a;
        res[6 * c + 3] = expf(fminf(fmaxf(o[6 * c + 3], -10.0f), 10.0f));
        res[6 * c + 4] = expf(fminf(fmaxf(o[6 * c + 4], -10.0f), 10.0f));
        res[6 * c + 5] = 0.99f * tanhf(o[6 * c + 5]);
    }
    float4* og = reinterpret_cast<float4*>(gmm_out + (size_t)gi * NOUT);
#pragma unroll
    for (int q = 0; q < NOUT / 4; ++q)
        og[q] = make_float4(res[4 * q + 0], res[4 * q + 1], res[4 * q + 2], res[4 * q + 3]);
    reinterpret_cast<float2*>(coords_out)[gi] = make_float2(cx, cy);
}

// ================= K1: gather + layer1, transposed store =================
__global__ __launch_bounds__(128, 4) void k1_gather_l1(
    const float* __restrict__ coords, const float* __restrict__ grid,
    const float* __restrict__ W1, const float* __restrict__ b1,
    float* __restrict__ h1t, int start, int cn)
{
#pragma clang fp contract(off)
    const int lane = threadIdx.x & 63;
    const int halfu = __builtin_amdgcn_readfirstlane((int)(threadIdx.x >> 6)); // wave-uniform j-half
    const int pt = blockIdx.x * 64 + lane;
    if (pt >= cn) return;
    const int gi = start + pt;

    const float2 c2 = reinterpret_cast<const float2*>(coords)[gi];
    const float cx = c2.x, cy = c2.y;
    const float x = cx * 63.0f;
    const float y = cy * 63.0f;
    int x0 = (int)floorf(x); x0 = x0 < 0 ? 0 : (x0 > 62 ? 62 : x0);
    int y0 = (int)floorf(y); y0 = y0 < 0 ? 0 : (y0 > 62 ? 62 : y0);
    const float dx = x - (float)x0;
    const float dy = y - (float)y0;
    const float omdx = 1.0f - dx;
    const float omdy = 1.0f - dy;
    const float w00 = omdx * omdy;
    const float w01 = omdx * dy;
    const float w10 = dx * omdy;
    const float w11 = dx * dy;
    const float* __restrict__ gp = grid + (y0 * GW + x0) * FDIM;

    // feat in registers, fully static
    float f[DIN];
    f[0] = cx; f[1] = cy;
#pragma unroll
    for (int k = 0; k < FDIM; ++k) {
        const float t0 = w00 * gp[k];
        const float t1 = w01 * gp[GW * FDIM + k];
        const float t2 = w10 * gp[FDIM + k];
        const float t3 = w11 * gp[GW * FDIM + FDIM + k];
        f[2 + k] = ((t0 + t1) + t2) + t3;
    }

    // GEMM1 half: j in [halfu*64, halfu*64+64), k fully unrolled (f[] static)
    float acc[64];
#pragma unroll
    for (int j = 0; j < 64; ++j) acc[j] = 0.0f;
    const float* __restrict__ wb = W1 + halfu * 64;
#pragma unroll
    for (int k = 0; k < DIN; ++k) {
        const float hv = f[k];
        const float* wr = wb + k * NH1;
#pragma unroll
        for (int q = 0; q < 16; ++q) {
            const float4 w = *reinterpret_cast<const float4*>(wr + 4 * q);
            acc[4*q+0] = __builtin_fmaf(hv, w.x, acc[4*q+0]);
            acc[4*q+1] = __builtin_fmaf(hv, w.y, acc[4*q+1]);
            acc[4*q+2] = __builtin_fmaf(hv, w.z, acc[4*q+2]);
            acc[4*q+3] = __builtin_fmaf(hv, w.w, acc[4*q+3]);
        }
    }

    // bias + relu, transposed coalesced store (post-relu raw h1)
    const float* __restrict__ bb = b1 + halfu * 64;
    float* __restrict__ outb = h1t + (size_t)(halfu * 64) * cn + pt;
#pragma unroll
    for (int jj = 0; jj < 64; ++jj)
        outb[(size_t)jj * cn] = fmaxf(acc[jj] + bb[jj], 0.0f);
}

// ================= K23: LN1 + layer2 + LN2 + layer3 + postproc =================
__global__ __launch_bounds__(256, 3) void k23_mlp(
    const float* __restrict__ h1t,
    const float* __restrict__ g1, const float* __restrict__ be1,
    const float* __restrict__ W2, const float* __restrict__ b2,
    const float* __restrict__ g2, const float* __restrict__ be2,
    const float* __restrict__ W3, const float* __restrict__ b3,
    const float* __restrict__ coords,
    float* __restrict__ gmm_out, float* __restrict__ coords_out,
    int start, int cn)
{
#pragma clang fp contract(off)
    const int pt = blockIdx.x * 256 + threadIdx.x;
    if (pt >= cn) return;                 // no LDS, no barriers: safe
    const int gi = start + pt;
    const float* __restrict__ col = h1t + pt;

    // ---- LN1 stats, numpy r[8] pattern streamed from h1t (coalesced) ----
    float r[8];
#pragma unroll
    for (int j = 0; j < 8; ++j) r[j] = col[(size_t)j * cn];
#pragma unroll
    for (int m = 1; m < 16; ++m)
#pragma unroll
        for (int j = 0; j < 8; ++j) r[j] = r[j] + col[(size_t)(8 * m + j) * cn];
    const float mu1 = (((r[0]+r[1]) + (r[2]+r[3])) + ((r[4]+r[5]) + (r[6]+r[7]))) / 128.0f;
#pragma unroll
    for (int j = 0; j < 8; ++j) { const float d = col[(size_t)j * cn] - mu1; r[j] = d * d; }
#pragma unroll
    for (int m = 1; m < 16; ++m)
#pragma unroll
        for (int j = 0; j < 8; ++j) {
            const float d = col[(size_t)(8 * m + j) * cn] - mu1;
            r[j] = r[j] + d * d;
        }
    const float var1 = (((r[0]+r[1]) + (r[2]+r[3])) + ((r[4]+r[5]) + (r[6]+r[7]))) / 128.0f;
    const float rs1 = 1.0f / sqrtf(var1 + 1e-5f);

    // ---- layer 2: 128 -> 64, normalize on the fly (identical rounding) ----
    float acc[NH2];
#pragma unroll
    for (int j = 0; j < NH2; ++j) acc[j] = 0.0f;
    for (int k = 0; k < NH1; ++k) {
        const float raw = col[(size_t)k * cn];
        const float hv = ((raw - mu1) * rs1) * g1[k] + be1[k];
        const float* wr = W2 + k * NH2;
#pragma unroll
        for (int q = 0; q < 16; ++q) {
            const float4 w = *reinterpret_cast<const float4*>(wr + 4 * q);
            acc[4*q+0] = __builtin_fmaf(hv, w.x, acc[4*q+0]);
            acc[4*q+1] = __builtin_fmaf(hv, w.y, acc[4*q+1]);
            acc[4*q+2] = __builtin_fmaf(hv, w.z, acc[4*q+2]);
            acc[4*q+3] = __builtin_fmaf(hv, w.w, acc[4*q+3]);
        }
    }
#pragma unroll
    for (int j = 0; j < NH2; ++j) acc[j] = fmaxf(acc[j] + b2[j], 0.0f);

    // ---- layernorm 2 (in-register, numpy pairwise) ----
    const float mu2 = np_pairwise<NH2>(acc) / 64.0f;
    const float var2 = np_pairwise_sq<NH2>(acc, mu2) / 64.0f;
    const float rs2 = 1.0f / sqrtf(var2 + 1e-5f);
#pragma unroll
    for (int j = 0; j < NH2; ++j)
        acc[j] = ((acc[j] - mu2) * rs2) * g2[j] + be2[j];

    // ---- layer 3: 64 -> 48, k fully unrolled (acc[] static indices) ----
    float o[NOUT];
#pragma unroll
    for (int j = 0; j < NOUT; ++j) o[j] = 0.0f;
#pragma unroll
    for (int k = 0; k < NH2; ++k) {
        const float hv = acc[k];
        const float* wr = W3 + k * NOUT;
#pragma unroll
        for (int q = 0; q < 12; ++q) {
            const float4 w = *reinterpret_cast<const float4*>(wr + 4 * q);
            o[4*q+0] = __builtin_fmaf(hv, w.x, o[4*q+0]);
            o[4*q+1] = __builtin_fmaf(hv, w.y, o[4*q+1]);
            o[4*q+2] = __builtin_fmaf(hv, w.z, o[4*q+2]);
            o[4*q+3] = __builtin_fmaf(hv, w.w, o[4*q+3]);
        }
    }
#pragma unroll
    for (int j = 0; j < NOUT; ++j) o[j] = o[j] + b3[j];

    const float2 c2 = reinterpret_cast<const float2*>(coords)[gi];
    gmm_postprocess_store(o, c2.x, c2.y, gi, gmm_out, coords_out);
}

// ================= fallback: round-3 monolith (proven, 563 us) =================
constexpr int BLK = 128;
__global__ __launch_bounds__(BLK, 2) void modgmm_np32(
    const float* __restrict__ coords,
    const float* __restrict__ grid,
    const float* __restrict__ W1, const float* __restrict__ b1,
    const float* __restrict__ g1, const float* __restrict__ be1,
    const float* __restrict__ W2, const float* __restrict__ b2,
    const float* __restrict__ g2, const float* __restrict__ be2,
    const float* __restrict__ W3, const float* __restrict__ b3,
    float* __restrict__ gmm_out, float* __restrict__ coords_out)
{
#pragma clang fp contract(off)
    __shared__ float sbuf[64 * BLK];
    const int tid = threadIdx.x;
    const int i = blockIdx.x * BLK + tid;
    if (i >= N_PTS) return;

    const float2 c2 = reinterpret_cast<const float2*>(coords)[i];
    const float cx = c2.x, cy = c2.y;
    const float x = cx * 63.0f;
    const float y = cy * 63.0f;
    int x0 = (int)floorf(x); x0 = x0 < 0 ? 0 : (x0 > 62 ? 62 : x0);
    int y0 = (int)floorf(y); y0 = y0 < 0 ? 0 : (y0 > 62 ? 62 : y0);
    const float dx = x - (float)x0;
    const float dy = y - (float)y0;
    const float omdx = 1.0f - dx;
    const float omdy = 1.0f - dy;
    const float w00 = omdx * omdy;
    const float w01 = omdx * dy;
    const float w10 = dx * omdy;
    const float w11 = dx * dy;
    const float* __restrict__ gp = grid + (y0 * GW + x0) * FDIM;

    sbuf[0 * BLK + tid] = cx;
    sbuf[1 * BLK + tid] = cy;
#pragma unroll
    for (int k = 0; k < FDIM; ++k) {
        const float t0 = w00 * gp[k];
        const float t1 = w01 * gp[GW * FDIM + k];
        const float t2 = w10 * gp[FDIM + k];
        const float t3 = w11 * gp[GW * FDIM + FDIM + k];
        sbuf[(2 + k) * BLK + tid] = ((t0 + t1) + t2) + t3;
    }

    float h[NH1];
#pragma unroll
    for (int j = 0; j < NH1; ++j) h[j] = 0.0f;
    for (int k = 0; k < DIN; ++k) {
        const float hv = sbuf[k * BLK + tid];
        const float* __restrict__ wr = W1 + k * NH1;
#pragma unroll
        for (int j = 0; j < NH1; ++j) h[j] = __builtin_fmaf(hv, wr[j], h[j]);
    }
#pragma unroll
    for (int j = 0; j < NH1; ++j) h[j] = fmaxf(h[j] + b1[j], 0.0f);
    {
        const float mu = np_pairwise<NH1>(h) / 128.0f;
        const float var = np_pairwise_sq<NH1>(h, mu) / 128.0f;
        const float rs = 1.0f / sqrtf(var + 1e-5f);
#pragma unroll
        for (int j = 0; j < NH1; ++j)
            h[j] = ((h[j] - mu) * rs) * g1[j] + be1[j];
    }

    float h2[NH2];
#pragma unroll
    for (int j = 0; j < NH2; ++j) h2[j] = 0.0f;
#pragma unroll
    for (int j = 0; j < 64; ++j) sbuf[j * BLK + tid] = h[j];
    for (int k = 0; k < 64; ++k) {
        const float hv = sbuf[k * BLK + tid];
        const float* __restrict__ wr = W2 + k * NH2;
#pragma unroll
        for (int j = 0; j < NH2; ++j) h2[j] = __builtin_fmaf(hv, wr[j], h2[j]);
    }
#pragma unroll
    for (int j = 0; j < 64; ++j) sbuf[j * BLK + tid] = h[64 + j];
    for (int k = 0; k < 64; ++k) {
        const float hv = sbuf[k * BLK + tid];
        const float* __restrict__ wr = W2 + (64 + k) * NH2;
#pragma unroll
        for (int j = 0; j < NH2; ++j) h2[j] = __builtin_fmaf(hv, wr[j], h2[j]);
    }
#pragma unroll
    for (int j = 0; j < NH2; ++j) h2[j] = fmaxf(h2[j] + b2[j], 0.0f);
    {
        const float mu = np_pairwise<NH2>(h2) / 64.0f;
        const float var = np_pairwise_sq<NH2>(h2, mu) / 64.0f;
        const float rs = 1.0f / sqrtf(var + 1e-5f);
#pragma unroll
        for (int j = 0; j < NH2; ++j)
            h2[j] = ((h2[j] - mu) * rs) * g2[j] + be2[j];
    }

    float o[NOUT];
#pragma unroll
    for (int j = 0; j < NOUT; ++j) o[j] = 0.0f;
#pragma unroll
    for (int j = 0; j < NH2; ++j) sbuf[j * BLK + tid] = h2[j];
    for (int k = 0; k < NH2; ++k) {
        const float hv = sbuf[k * BLK + tid];
        const float* __restrict__ wr = W3 + k * NOUT;
#pragma unroll
        for (int j = 0; j < NOUT; ++j) o[j] = __builtin_fmaf(hv, wr[j], o[j]);
    }
#pragma unroll
    for (int j = 0; j < NOUT; ++j) o[j] = o[j] + b3[j];

    gmm_postprocess_store(o, cx, cy, i, gmm_out, coords_out);
}

extern "C" void kernel_launch(void* const* d_in, const int* in_sizes, int n_in,
                              void* d_out, int out_size, void* d_ws, size_t ws_size,
                              hipStream_t stream) {
    const float* coords = (const float*)d_in[0];
    const float* grid   = (const float*)d_in[1];
    const float* W1  = (const float*)d_in[2];
    const float* b1  = (const float*)d_in[3];
    const float* g1  = (const float*)d_in[4];
    const float* be1 = (const float*)d_in[5];
    const float* W2  = (const float*)d_in[6];
    const float* b2  = (const float*)d_in[7];
    const float* g2  = (const float*)d_in[8];
    const float* be2 = (const float*)d_in[9];
    const float* W3  = (const float*)d_in[10];
    const float* b3  = (const float*)d_in[11];

    float* gmm_out    = (float*)d_out;                          // N*48 floats
    float* coords_out = (float*)d_out + (size_t)N_PTS * NOUT;   // N*2 floats
    float* h1t = (float*)d_ws;                                  // [128][chunk]

    const size_t cap_pts = ws_size / ((size_t)NH1 * sizeof(float));  // 512 B/pt
    int CH = (int)(cap_pts < (size_t)N_PTS ? cap_pts : (size_t)N_PTS);
    CH &= ~255;                                                 // multiple of 256

    if (CH >= 131072 || CH >= N_PTS) {
        for (int s = 0; s < N_PTS; s += CH) {
            const int cn = (N_PTS - s) < CH ? (N_PTS - s) : CH;
            const int b1blocks = (cn + 63) / 64;
            k1_gather_l1<<<b1blocks, 128, 0, stream>>>(
                coords, grid, W1, b1, h1t, s, cn);
            const int b2blocks = (cn + 255) / 256;
            k23_mlp<<<b2blocks, 256, 0, stream>>>(
                h1t, g1, be1, W2, b2, g2, be2, W3, b3, coords,
                gmm_out, coords_out, s, cn);
        }
    } else {
        // ws too small: proven round-3 monolith
        const int nblocks = (N_PTS + BLK - 1) / BLK;
        modgmm_np32<<<nblocks, BLK, 0, stream>>>(
            coords, grid, W1, b1, g1, be1, W2, b2, g2, be2, W3, b3,
            gmm_out, coords_out);
    }
}